// Round 1
// baseline (1545.936 us; speedup 1.0000x reference)
//
#include <hip/hip_runtime.h>
#include <stdint.h>

typedef unsigned short u16;
typedef unsigned int u32;
typedef __bf16 bf16x8 __attribute__((ext_vector_type(8)));
typedef float floatx4 __attribute__((ext_vector_type(4)));

#define NEG_INF_F (-10000000.0f)
#define MFMA16 __builtin_amdgcn_mfma_f32_16x16x32_bf16

__device__ __forceinline__ float bf2f(u16 u) {
    union { u32 u; float f; } x; x.u = ((u32)u) << 16; return x.f;
}
__device__ __forceinline__ u16 f2bf(float f) {
    union { float f; u32 u; } x; x.f = f;
    u32 r = x.u + 0x7fffu + ((x.u >> 16) & 1u);   // RNE
    return (u16)(r >> 16);
}

__device__ __forceinline__ void async_cp16(const void* g, void* l) {
    __builtin_amdgcn_global_load_lds(
        (const __attribute__((address_space(1))) void*)g,
        (__attribute__((address_space(3))) void*)l, 16, 0, 0);
}

// ---------------------------------------------------------------------------
// BT GEMM: C[m,n] = sum_k A[m,k] * B[n,k]
// 128x128 tile, 256 threads (4 waves 2x2), mfma_f32_16x16x32_bf16, BK=64,
// global_load_lds width-16 staging + 16B-group XOR swizzle (conflict-free).
// Retained for LOGITS / CTX / OUT (triangular + small-N shapes).
// ---------------------------------------------------------------------------
enum { EPI_QKV = 0, EPI_LOGITS = 1, EPI_CTX = 2, EPI_MLP = 3, EPI_OUT = 4 };

template <int EPI>
__global__ __launch_bounds__(256) void gemm_bt(
    const u16* __restrict__ A, int lda, long long aBatch,
    const u16* __restrict__ B, int ldb, long long bBatch,
    void* __restrict__ Cv, int ldc, long long cBatch,
    int K,
    const float* __restrict__ bias,
    const u16* __restrict__ ctxb,
    u16* __restrict__ xb,
    float scale, int nx, int ny)
{
    __shared__ __align__(16) u16 sA[128 * 64];   // 16 KB
    __shared__ __align__(16) u16 sB[128 * 64];   // 16 KB

    const int tid  = threadIdx.x;
    const int wave = tid >> 6;
    const int lane = tid & 63;

    int bxE, byE, bz;
    if constexpr (EPI == EPI_LOGITS) {
        bz = blockIdx.x & 7;
        int t = blockIdx.x >> 3;                       // 0..35 triangular
        int tq = (int)((sqrtf(8.0f * t + 1.0f) - 1.0f) * 0.5f);
        while ((tq + 1) * (tq + 2) / 2 <= t) ++tq;
        while (tq * (tq + 1) / 2 > t) --tq;
        bxE = tq;                       // n-tile = query
        byE = t - tq * (tq + 1) / 2;    // m-tile = key (<= tq)
    } else if constexpr (EPI == EPI_CTX) {
        bz = blockIdx.x & 7;
        int t = blockIdx.x >> 3;        // 0..63
        bxE = t & 7;                    // h-tile
        byE = t >> 3;                   // q-tile
    } else {
        bz = 0;
        const int k = blockIdx.x & 7, r = blockIdx.x >> 3;
        if (nx >= 8) { const int xp = nx >> 3; bxE = xp * k + (r % xp); byE = r / xp; }
        else         { bxE = k >> 1; byE = (k & 1) * (ny >> 1) + r; }
    }
    int Keff = K;
    if constexpr (EPI == EPI_CTX) Keff = min(K, (byE + 1) * 128);

    const u16* Ab = A + (long long)bz * aBatch + (long long)(byE * 128) * lda;
    const u16* Bb = B + (long long)bz * bBatch + (long long)(bxE * 128) * ldb;

    const int wm = wave >> 1, wn = wave & 1;
    const int quad = lane >> 4;

    const int srowoff = lane >> 3;
    const int gf      = (lane & 7) ^ ((lane >> 3) & 7);

    const int ra = 64 * wm + (lane & 15);
    const int rb = 64 * wn + (lane & 15);
    const int rx7 = lane & 7;

    floatx4 zero = {0.f, 0.f, 0.f, 0.f};
    floatx4 acc[4][4];
#pragma unroll
    for (int i = 0; i < 4; ++i)
#pragma unroll
        for (int j = 0; j < 4; ++j) acc[i][j] = zero;

    for (int k0 = 0; k0 < Keff; k0 += 64) {
#pragma unroll
        for (int i = 0; i < 4; ++i) {
            const int c = wave * 4 + i;
            const int r = c * 8 + srowoff;
            async_cp16(Ab + (long long)r * lda + k0 + gf * 8, &sA[c * 512 + lane * 8]);
            async_cp16(Bb + (long long)r * ldb + k0 + gf * 8, &sB[c * 512 + lane * 8]);
        }
        __syncthreads();

#pragma unroll
        for (int kk = 0; kk < 64; kk += 32) {
            const int gbase = kk >> 3;
            const int ga = ((gbase + quad) ^ rx7) << 3;
            bf16x8 af[4], bf[4];
#pragma unroll
            for (int mi = 0; mi < 4; ++mi)
                af[mi] = *(const bf16x8*)&sA[(ra + 16 * mi) * 64 + ga];
#pragma unroll
            for (int ni = 0; ni < 4; ++ni)
                bf[ni] = *(const bf16x8*)&sB[(rb + 16 * ni) * 64 + ga];
#pragma unroll
            for (int mi = 0; mi < 4; ++mi)
#pragma unroll
                for (int ni = 0; ni < 4; ++ni)
                    acc[mi][ni] = MFMA16(af[mi], bf[ni], acc[mi][ni], 0, 0, 0);
        }
        __syncthreads();
    }

    const int m0 = byE * 128 + 64 * wm + (quad << 2);
    const int n0 = bxE * 128 + 64 * wn + (lane & 15);
#pragma unroll
    for (int mi = 0; mi < 4; ++mi) {
#pragma unroll
        for (int ni = 0; ni < 4; ++ni) {
            const int gn = n0 + ni * 16;
#pragma unroll
            for (int r = 0; r < 4; ++r) {
                const int gm = m0 + mi * 16 + r;
                float v = acc[mi][ni][r];
                if constexpr (EPI == EPI_QKV) {
                    v += bias[gn];
                    ((u16*)Cv)[(long long)gm * ldc + gn] = f2bf(v);
                } else if constexpr (EPI == EPI_LOGITS) {
                    v = v * scale + (gm > gn ? NEG_INF_F : 0.0f);  // m=key, n=query
                    ((float*)Cv)[(long long)bz * cBatch + (long long)gm * ldc + gn] = v;
                } else if constexpr (EPI == EPI_CTX) {
                    ((u16*)Cv)[(long long)bz * cBatch + (long long)gm * ldc + gn] = f2bf(v);
                } else if constexpr (EPI == EPI_MLP) {
                    const long long idx = (long long)gm * ldc + gn;
                    v += bias[gn];
                    v = fmaxf(v, 0.0f);
                    float xv = bf2f(xb[idx]) + bf2f(ctxb[idx]) + v;
                    xb[idx] = f2bf(xv);
                } else {  // EPI_OUT
                    v += bias[gn];
                    ((float*)Cv)[(long long)gm * ldc + gn] = v;
                }
            }
        }
    }
}

// ---------------------------------------------------------------------------
// gemm3s: 3-stage counted-vmcnt pipelined BT GEMM (T3+T4+T5 port).
//   BM=256, BN=128, BK=64, 512 threads = 8 waves (4m x 2n, 64x64 C/wave).
//   LDS 144 KB: 3 x (A 32KB + B 16KB) rotating buffers. While computing
//   tile t from buf[t%3], stage tile t+2 into buf[(t+2)%3] -> no intra-tile
//   write/read overlap, ONE raw s_barrier + ONE s_waitcnt vmcnt(6) per
//   K-tile (6 global_load_lds/thread/tile: vmcnt(6) retires exactly tile
//   t+1's loads, tile t+2's stay in flight across the barrier).
//   Same XOR source-swizzle + swizzled LDS read as gemm_bt (rule-21 pair).
//   Requires M == 8192 (32 m-tiles = 8 XCD x 4). Grid = 8 * 4 * n_tiles.
//   Decode: XCD k owns m-tiles [4k,4k+4); r>>2 sweeps n with A-panel (2 MB)
//   L2-resident and B-tile (256 KB) reused 4x.
// ---------------------------------------------------------------------------
template <int EPI>
__global__ __launch_bounds__(512, 2) void gemm3s(
    const u16* __restrict__ A, int lda,
    const u16* __restrict__ Bw, int ldb,
    void* __restrict__ Cv, int ldc,
    int K, const float* __restrict__ bias,
    const u16* __restrict__ ctxb, u16* __restrict__ xb)
{
    __shared__ __align__(16) u16 sA[3][256 * 64];   // 3 x 32 KB
    __shared__ __align__(16) u16 sB[3][128 * 64];   // 3 x 16 KB

    const int tid  = threadIdx.x;
    const int wave = tid >> 6;
    const int lane = tid & 63;
    const int wm   = wave >> 1, wn = wave & 1;      // 4 x 2 wave grid
    const int quad = lane >> 4;

    const int k8 = blockIdx.x & 7;
    const int r  = blockIdx.x >> 3;
    const int bxE = r >> 2;                         // n-tile (128 wide)
    const int byE = k8 * 4 + (r & 3);               // m-tile (256 tall)

    const u16* Ab = A  + (long long)(byE * 256) * lda;
    const u16* Bb = Bw + (long long)(bxE * 128) * ldb;

    // staging: call c covers rows c*64 + (tid>>3); col-group XOR swizzle.
    const int srow = tid >> 3;                      // 0..63
    const int gf   = (tid & 7) ^ ((tid >> 3) & 7);
    const long long aSrc = (long long)srow * lda + gf * 8;
    const long long bSrc = (long long)srow * ldb + gf * 8;
    const int dst = (wave << 9) + lane * 8;         // (wave*8)*64 + lane*8

#define STA(nb, c, k0) async_cp16(Ab + (long long)((c) * 64) * lda + (k0) + aSrc, \
                                  &sA[nb][(c) * 4096 + dst])
#define STB(nb, c, k0) async_cp16(Bb + (long long)((c) * 64) * ldb + (k0) + bSrc, \
                                  &sB[nb][(c) * 4096 + dst])

    const int ra  = wm * 64 + (lane & 15);
    const int rb  = wn * 64 + (lane & 15);
    const int rx7 = lane & 7;

    floatx4 zero = {0.f, 0.f, 0.f, 0.f};
    floatx4 acc[4][4];
#pragma unroll
    for (int i = 0; i < 4; ++i)
#pragma unroll
        for (int j = 0; j < 4; ++j) acc[i][j] = zero;

    const int NT = K >> 6;                          // 16 for K=1024

    // prologue: tiles 0 and 1 (6 loads/thread each)
    STA(0, 0, 0);  STA(0, 1, 0);  STA(0, 2, 0);  STA(0, 3, 0);
    STB(0, 0, 0);  STB(0, 1, 0);
    STA(1, 0, 64); STA(1, 1, 64); STA(1, 2, 64); STA(1, 3, 64);
    STB(1, 0, 64); STB(1, 1, 64);

    int cb = 0;
#pragma unroll 3
    for (int t = 0; t < NT; ++t) {
        // tile t's data ready when only tile t+1's 6 loads remain in flight
        if (t + 1 < NT) asm volatile("s_waitcnt vmcnt(6)" ::: "memory");
        else            asm volatile("s_waitcnt vmcnt(0)" ::: "memory");
        __builtin_amdgcn_s_barrier();

        const int  nb = (cb == 0) ? 2 : cb - 1;     // (t+2) % 3
        const int  kn = (t + 2) << 6;
        const bool st = (t + 2) < NT;
        const u16* pA = &sA[cb][0];
        const u16* pB = &sB[cb][0];

        bf16x8 af[4], bf0, bf1;

        // ---- phase 0: kk=0, n-half 0 | stage A rows 0..127 of tile t+2
        if (st) { STA(nb, 0, kn); STA(nb, 1, kn); }
        {
            const int g = (quad ^ rx7) << 3;
#pragma unroll
            for (int mi = 0; mi < 4; ++mi)
                af[mi] = *(const bf16x8*)&pA[(ra + 16 * mi) * 64 + g];
            bf0 = *(const bf16x8*)&pB[rb * 64 + g];
            bf1 = *(const bf16x8*)&pB[(rb + 16) * 64 + g];
        }
        __builtin_amdgcn_s_setprio(1);
#pragma unroll
        for (int mi = 0; mi < 4; ++mi) {
            acc[mi][0] = MFMA16(af[mi], bf0, acc[mi][0], 0, 0, 0);
            acc[mi][1] = MFMA16(af[mi], bf1, acc[mi][1], 0, 0, 0);
        }
        __builtin_amdgcn_s_setprio(0);

        // ---- phase 1: kk=0, n-half 1 | stage A rows 128..255
        if (st) { STA(nb, 2, kn); STA(nb, 3, kn); }
        {
            const int g = (quad ^ rx7) << 3;
            bf0 = *(const bf16x8*)&pB[(rb + 32) * 64 + g];
            bf1 = *(const bf16x8*)&pB[(rb + 48) * 64 + g];
        }
        __builtin_amdgcn_s_setprio(1);
#pragma unroll
        for (int mi = 0; mi < 4; ++mi) {
            acc[mi][2] = MFMA16(af[mi], bf0, acc[mi][2], 0, 0, 0);
            acc[mi][3] = MFMA16(af[mi], bf1, acc[mi][3], 0, 0, 0);
        }
        __builtin_amdgcn_s_setprio(0);

        // ---- phase 2: kk=32, n-half 0 | stage B rows 0..63
        if (st) { STB(nb, 0, kn); }
        {
            const int g = ((4 + quad) ^ rx7) << 3;
#pragma unroll
            for (int mi = 0; mi < 4; ++mi)
                af[mi] = *(const bf16x8*)&pA[(ra + 16 * mi) * 64 + g];
            bf0 = *(const bf16x8*)&pB[rb * 64 + g];
            bf1 = *(const bf16x8*)&pB[(rb + 16) * 64 + g];
        }
        __builtin_amdgcn_s_setprio(1);
#pragma unroll
        for (int mi = 0; mi < 4; ++mi) {
            acc[mi][0] = MFMA16(af[mi], bf0, acc[mi][0], 0, 0, 0);
            acc[mi][1] = MFMA16(af[mi], bf1, acc[mi][1], 0, 0, 0);
        }
        __builtin_amdgcn_s_setprio(0);

        // ---- phase 3: kk=32, n-half 1 | stage B rows 64..127
        if (st) { STB(nb, 1, kn); }
        {
            const int g = ((4 + quad) ^ rx7) << 3;
            bf0 = *(const bf16x8*)&pB[(rb + 32) * 64 + g];
            bf1 = *(const bf16x8*)&pB[(rb + 48) * 64 + g];
        }
        __builtin_amdgcn_s_setprio(1);
#pragma unroll
        for (int mi = 0; mi < 4; ++mi) {
            acc[mi][2] = MFMA16(af[mi], bf0, acc[mi][2], 0, 0, 0);
            acc[mi][3] = MFMA16(af[mi], bf1, acc[mi][3], 0, 0, 0);
        }
        __builtin_amdgcn_s_setprio(0);

        cb = (cb == 2) ? 0 : cb + 1;
    }
#undef STA
#undef STB

    // epilogue: C/D layout col = lane&15, row = (lane>>4)*4 + reg
    const int m0 = byE * 256 + wm * 64 + (quad << 2);
    const int n0 = bxE * 128 + wn * 64 + (lane & 15);
#pragma unroll
    for (int mi = 0; mi < 4; ++mi) {
#pragma unroll
        for (int ni = 0; ni < 4; ++ni) {
            const int gn = n0 + ni * 16;
            const float bb = bias[gn];
#pragma unroll
            for (int rr = 0; rr < 4; ++rr) {
                const int gm = m0 + mi * 16 + rr;
                float v = acc[mi][ni][rr] + bb;
                if constexpr (EPI == EPI_QKV) {
                    ((u16*)Cv)[(long long)gm * ldc + gn] = f2bf(v);
                } else {  // EPI_MLP
                    const long long idx = (long long)gm * ldc + gn;
                    v = fmaxf(v, 0.0f);
                    float xv = bf2f(xb[idx]) + bf2f(ctxb[idx]) + v;
                    xb[idx] = f2bf(xv);
                }
            }
        }
    }
}

// ---------------------------------------------------------------------------
// Setup mega-kernel: weight transposes (f32->bf16) + bias packing.
// ---------------------------------------------------------------------------
template <int L, int H, int V>
__global__ void setup_weights(const float* __restrict__ Wq, const float* __restrict__ Wk,
                              const float* __restrict__ Wv, const float* __restrict__ Wm,
                              const float* __restrict__ Wout,
                              const float* __restrict__ bq, const float* __restrict__ bk,
                              const float* __restrict__ bv,
                              u16* __restrict__ WqkvT, u16* __restrict__ WmT,
                              u16* __restrict__ WoutT, float* __restrict__ bqkv)
{
    const int z = blockIdx.z;
    if (z == 4 * L + 1) {
        int i = ((blockIdx.y * 16 + blockIdx.x) * 256) + threadIdx.y * 64 + threadIdx.x;
        if (i < L * 3 * H) {
            int l = i / (3 * H), j = i % (3 * H);
            float v = (j < H) ? bq[l * H + j]
                    : (j < 2 * H) ? bk[l * H + j - H]
                                  : bv[l * H + j - 2 * H];
            bqkv[i] = v;
        }
        return;
    }

    const float* in;
    u16* outp;
    int inStride, outStride;
    if (z == 4 * L) {
        if (blockIdx.x >= V / 64) return;
        in = Wout; inStride = V;
        outp = WoutT; outStride = H;
    } else {
        const int which = z / L, l = z % L;
        inStride = H; outStride = H;
        if (which == 3) { in = Wm + (long long)l * H * H; outp = WmT + (long long)l * H * H; }
        else {
            in   = (which == 0 ? Wq : which == 1 ? Wk : Wv) + (long long)l * H * H;
            outp = WqkvT + (long long)l * 3 * H * H + (long long)which * H * H;
        }
    }

    __shared__ float tile[64][65];
    const int r0 = blockIdx.y * 64, c0 = blockIdx.x * 64;
    const int x = threadIdx.x, y = threadIdx.y;
#pragma unroll
    for (int j = 0; j < 16; ++j) {
        int r = y + j * 4;
        tile[r][x] = in[(long long)(r0 + r) * inStride + c0 + x];
    }
    __syncthreads();
#pragma unroll
    for (int j = 0; j < 16; ++j) {
        int r = y + j * 4;
        outp[(long long)(c0 + r) * outStride + r0 + x] = f2bf(tile[x][r]);
    }
}

// ---------------------------------------------------------------------------
// Merged attention post-processing (softmax + attnT, V->Vt transpose).
// ---------------------------------------------------------------------------
__global__ __launch_bounds__(1024) void attn_post(
    float* __restrict__ attn, long long aStride,
    u16* __restrict__ attnT, long long tStride,
    const u16* __restrict__ qkv, u16* __restrict__ Vt)
{
    const int zone = blockIdx.y;
    if (zone < 8) {
        __shared__ float sm[64][16], sl[64][16], sm2[8][16], sl2[8][16];
        __shared__ float sM[16], sInv[16];

        float* base = attn + (long long)zone * aStride;
        const int x = threadIdx.x, ky = threadIdx.y;
        const int q = blockIdx.x * 16 + x;

        float v[16];
        float m = -3.4e38f, l = 0.f;
#pragma unroll
        for (int j = 0; j < 16; ++j) {
            const int k = ky * 16 + j;
            float vj = NEG_INF_F;
            if (k <= q) vj = base[(long long)k * 1024 + q];
            v[j] = vj;
            float mn = fmaxf(m, vj);
            l = l * __expf(m - mn) + __expf(vj - mn);
            m = mn;
        }
        sm[ky][x] = m;
        sl[ky][x] = l;
        __syncthreads();
        if (ky < 8) {
            float M = -3.4e38f, L = 0.f;
#pragma unroll
            for (int t = 0; t < 8; ++t) {
                float mm = sm[ky + 8 * t][x], ll = sl[ky + 8 * t][x];
                float mn = fmaxf(M, mm);
                L = L * __expf(M - mn) + ll * __expf(mm - mn);
                M = mn;
            }
            sm2[ky][x] = M;
            sl2[ky][x] = L;
        }
        __syncthreads();
        if (ky == 0) {
            float M = -3.4e38f, L = 0.f;
#pragma unroll
            for (int t = 0; t < 8; ++t) {
                float mm = sm2[t][x], ll = sl2[t][x];
                float mn = fmaxf(M, mm);
                L = L * __expf(M - mn) + ll * __expf(mm - mn);
                M = mn;
            }
            sM[x]   = M;
            sInv[x] = 1.0f / L;
        }
        __syncthreads();
        const float M = sM[x], inv = sInv[x];

        u16 pb[16];
#pragma unroll
        for (int j = 0; j < 16; ++j) {
            float p = __expf(v[j] - M) * inv;
            base[(long long)(ky * 16 + j) * 1024 + q] = p;
            pb[j] = f2bf(p);
        }
        u16* trow = attnT + (long long)zone * tStride + (long long)q * 1024 + ky * 16;
        ((uint4*)trow)[0] = *(const uint4*)&pb[0];
        ((uint4*)trow)[1] = *(const uint4*)&pb[8];
    } else {
        const int b = zone - 8;
        const u16* Vb = qkv + 2 * 1024 + (long long)b * (1024LL * 3072);
        u16* Ob       = Vt + (long long)b * (1024LL * 1024);
        __shared__ float tile[64][65];
        const int tid = threadIdx.y * 16 + threadIdx.x;
        const int tx = tid & 63, ty = tid >> 6;
#pragma unroll
        for (int rep = 0; rep < 4; ++rep) {
            const int T = blockIdx.x + rep * 64;
            const int s0 = (T >> 4) * 64, h0 = (T & 15) * 64;
            __syncthreads();
#pragma unroll
            for (int j = 0; j < 4; ++j) {
                const int s = j * 16 + ty;
                tile[s][tx] = bf2f(Vb[(long long)(s0 + s) * 3072 + h0 + tx]);
            }
            __syncthreads();
#pragma unroll
            for (int j = 0; j < 4; ++j) {
                const int h = j * 16 + ty;
                Ob[(long long)(h0 + h) * 1024 + s0 + tx] = f2bf(tile[tx][h]);
            }
        }
    }
}

// ---------------------------------------------------------------------------
__global__ void embed_kernel(const int* __restrict__ tok, const float* __restrict__ emb,
                             u16* __restrict__ xb)
{
    const int row = blockIdx.x;
    const int t   = tok[row];
    float4 v = ((const float4*)(emb + (long long)t * 1024))[threadIdx.x];
    uint2 p;
    p.x = (u32)f2bf(v.x) | ((u32)f2bf(v.y) << 16);
    p.y = (u32)f2bf(v.z) | ((u32)f2bf(v.w) << 16);
    ((uint2*)(xb + (long long)row * 1024))[threadIdx.x] = p;
}

// ---------------------------------------------------------------------------
extern "C" void kernel_launch(void* const* d_in, const int* in_sizes, int n_in,
                              void* d_out, int out_size, void* d_ws, size_t ws_size,
                              hipStream_t stream)
{
    const int*   tok  = (const int*)d_in[0];
    const float* emb  = (const float*)d_in[1];
    const float* Wq   = (const float*)d_in[2];
    const float* bq   = (const float*)d_in[3];
    const float* Wk   = (const float*)d_in[4];
    const float* bk   = (const float*)d_in[5];
    const float* Wv   = (const float*)d_in[6];
    const float* bv   = (const float*)d_in[7];
    const float* Wm   = (const float*)d_in[8];
    const float* bm   = (const float*)d_in[9];
    const float* Wout = (const float*)d_in[10];
    const float* bout = (const float*)d_in[11];
    float* out = (float*)d_out;

    constexpr int B = 8, S = 1024, H = 1024, V = 512, L = 6;
    constexpr long long M = (long long)B * S;  // 8192

    char* ws = (char*)d_ws;
    u16*   WqkvT = (u16*)ws;   ws += (long long)L * 3 * H * H * 2;
    u16*   WmT   = (u16*)ws;   ws += (long long)L * H * H * 2;
    u16*   WoutT = (u16*)ws;   ws += (long long)V * H * 2;
    float* bqkv  = (float*)ws; ws += (long long)L * 3 * H * 4;
    u16*   xb    = (u16*)ws;   ws += M * H * 2;
    u16*   QKV   = (u16*)ws;   ws += M * 3 * H * 2;
    u16*   attnT = (u16*)ws;   ws += (long long)B * S * S * 2;
    u16*   Vt    = (u16*)ws;   ws += (long long)B * S * S * 2;
    u16*   ctxb  = (u16*)ws;   ws += M * H * 2;

    float* attnOut = out + (long long)B * S * V;

    setup_weights<L, H, V><<<dim3(16, 16, 4 * L + 2), dim3(64, 4), 0, stream>>>(
        Wq, Wk, Wv, Wm, Wout, bq, bk, bv, WqkvT, WmT, WoutT, bqkv);
    embed_kernel<<<M, 256, 0, stream>>>(tok, emb, xb);

    for (int l = 0; l < L; ++l) {
        // QKV = xb @ [Wq|Wk|Wv] + bias -> bf16 [M][3H]  (3-stage pipeline)
        gemm3s<EPI_QKV><<<768, 512, 0, stream>>>(
            xb, H, WqkvT + (long long)l * 3 * H * H, H,
            QKV, 3 * H, H, bqkv + l * 3 * H, nullptr, nullptr);

        // logits[k,q] = K . Q * scale + mask  (lower-triangle tiles, batch/XCD)
        float* attnL = attnOut + (long long)l * B * S * S;
        gemm_bt<EPI_LOGITS><<<288, 256, 0, stream>>>(
            QKV + H, 3 * H, (long long)S * 3 * H,
            QKV, 3 * H, (long long)S * 3 * H,
            attnL, S, (long long)S * S, H,
            nullptr, nullptr, nullptr, 0.03125f, 0, 0);

        // softmax+attnT emission (zones 0-7) and V->Vt transpose (zones 8-15)
        attn_post<<<dim3(64, 16), dim3(16, 64), 0, stream>>>(
            attnL, (long long)S * S, attnT, (long long)S * S, QKV, Vt);

        // ctx[q,h] = sum_{k<=q} attnT[q,k] * Vt[h,k]  -> bf16 (batch/XCD)
        gemm_bt<EPI_CTX><<<512, 256, 0, stream>>>(
            attnT, S, (long long)S * S, Vt, S, (long long)S * S,
            ctxb, H, (long long)S * H, S,
            nullptr, nullptr, nullptr, 0.f, 0, 0);

        // xb = bf16( xb + ctx + relu(ctx @ Wm + bm) )  (3-stage pipeline)
        gemm3s<EPI_MLP><<<256, 512, 0, stream>>>(
            ctxb, H, WmT + (long long)l * H * H, H,
            nullptr, H, H, bm + l * H, ctxb, xb);
    }

    // out = xb @ Wout + bout -> f32
    gemm_bt<EPI_OUT><<<256, 256, 0, stream>>>(
        xb, H, 0, WoutT, H, 0, out, V, 0, H,
        bout, nullptr, nullptr, 0.f, 4, 64);
}

// Round 2
// 1355.921 us; speedup vs baseline: 1.1401x; 1.1401x over previous
//
#include <hip/hip_runtime.h>
#include <stdint.h>

typedef unsigned short u16;
typedef unsigned int u32;
typedef __bf16 bf16x8 __attribute__((ext_vector_type(8)));
typedef float floatx4 __attribute__((ext_vector_type(4)));

#define NEG_INF_F (-10000000.0f)
#define MFMA16 __builtin_amdgcn_mfma_f32_16x16x32_bf16

__device__ __forceinline__ float bf2f(u16 u) {
    union { u32 u; float f; } x; x.u = ((u32)u) << 16; return x.f;
}
__device__ __forceinline__ u16 f2bf(float f) {
    union { float f; u32 u; } x; x.f = f;
    u32 r = x.u + 0x7fffu + ((x.u >> 16) & 1u);   // RNE
    return (u16)(r >> 16);
}

__device__ __forceinline__ void async_cp16(const void* g, void* l) {
    __builtin_amdgcn_global_load_lds(
        (const __attribute__((address_space(1))) void*)g,
        (__attribute__((address_space(3))) void*)l, 16, 0, 0);
}

// ---------------------------------------------------------------------------
// BT GEMM: C[m,n] = sum_k A[m,k] * B[n,k]
// 128x128 tile, 256 threads (4 waves 2x2), mfma_f32_16x16x32_bf16, BK=64,
// global_load_lds width-16 staging + 16B-group XOR swizzle (conflict-free).
// Used for LOGITS / CTX / MLP / OUT.
// ---------------------------------------------------------------------------
enum { EPI_QKV = 0, EPI_LOGITS = 1, EPI_CTX = 2, EPI_MLP = 3, EPI_OUT = 4 };

template <int EPI>
__global__ __launch_bounds__(256) void gemm_bt(
    const u16* __restrict__ A, int lda, long long aBatch,
    const u16* __restrict__ B, int ldb, long long bBatch,
    void* __restrict__ Cv, int ldc, long long cBatch,
    int K,
    const float* __restrict__ bias,
    const u16* __restrict__ ctxb,
    u16* __restrict__ xb,
    float scale, int nx, int ny)
{
    __shared__ __align__(16) u16 sA[128 * 64];   // 16 KB
    __shared__ __align__(16) u16 sB[128 * 64];   // 16 KB

    const int tid  = threadIdx.x;
    const int wave = tid >> 6;
    const int lane = tid & 63;

    int bxE, byE, bz;
    if constexpr (EPI == EPI_LOGITS) {
        bz = blockIdx.x & 7;
        int t = blockIdx.x >> 3;                       // 0..35 triangular
        int tq = (int)((sqrtf(8.0f * t + 1.0f) - 1.0f) * 0.5f);
        while ((tq + 1) * (tq + 2) / 2 <= t) ++tq;
        while (tq * (tq + 1) / 2 > t) --tq;
        bxE = tq;                       // n-tile = query
        byE = t - tq * (tq + 1) / 2;    // m-tile = key (<= tq)
    } else if constexpr (EPI == EPI_CTX) {
        bz = blockIdx.x & 7;
        int t = blockIdx.x >> 3;        // 0..63
        bxE = t & 7;                    // h-tile
        byE = t >> 3;                   // q-tile
    } else {
        bz = 0;
        const int k = blockIdx.x & 7, r = blockIdx.x >> 3;
        if (nx >= 8) { const int xp = nx >> 3; bxE = xp * k + (r % xp); byE = r / xp; }
        else         { bxE = k >> 1; byE = (k & 1) * (ny >> 1) + r; }
    }
    int Keff = K;
    if constexpr (EPI == EPI_CTX) Keff = min(K, (byE + 1) * 128);

    const u16* Ab = A + (long long)bz * aBatch + (long long)(byE * 128) * lda;
    const u16* Bb = B + (long long)bz * bBatch + (long long)(bxE * 128) * ldb;

    const int wm = wave >> 1, wn = wave & 1;
    const int quad = lane >> 4;

    const int srowoff = lane >> 3;
    const int gf      = (lane & 7) ^ ((lane >> 3) & 7);

    const int ra = 64 * wm + (lane & 15);
    const int rb = 64 * wn + (lane & 15);
    const int rx7 = lane & 7;

    floatx4 zero = {0.f, 0.f, 0.f, 0.f};
    floatx4 acc[4][4];
#pragma unroll
    for (int i = 0; i < 4; ++i)
#pragma unroll
        for (int j = 0; j < 4; ++j) acc[i][j] = zero;

    for (int k0 = 0; k0 < Keff; k0 += 64) {
#pragma unroll
        for (int i = 0; i < 4; ++i) {
            const int c = wave * 4 + i;
            const int r = c * 8 + srowoff;
            async_cp16(Ab + (long long)r * lda + k0 + gf * 8, &sA[c * 512 + lane * 8]);
            async_cp16(Bb + (long long)r * ldb + k0 + gf * 8, &sB[c * 512 + lane * 8]);
        }
        __syncthreads();

#pragma unroll
        for (int kk = 0; kk < 64; kk += 32) {
            const int gbase = kk >> 3;
            const int ga = ((gbase + quad) ^ rx7) << 3;
            bf16x8 af[4], bf[4];
#pragma unroll
            for (int mi = 0; mi < 4; ++mi)
                af[mi] = *(const bf16x8*)&sA[(ra + 16 * mi) * 64 + ga];
#pragma unroll
            for (int ni = 0; ni < 4; ++ni)
                bf[ni] = *(const bf16x8*)&sB[(rb + 16 * ni) * 64 + ga];
#pragma unroll
            for (int mi = 0; mi < 4; ++mi)
#pragma unroll
                for (int ni = 0; ni < 4; ++ni)
                    acc[mi][ni] = MFMA16(af[mi], bf[ni], acc[mi][ni], 0, 0, 0);
        }
        __syncthreads();
    }

    const int m0 = byE * 128 + 64 * wm + (quad << 2);
    const int n0 = bxE * 128 + 64 * wn + (lane & 15);
#pragma unroll
    for (int mi = 0; mi < 4; ++mi) {
#pragma unroll
        for (int ni = 0; ni < 4; ++ni) {
            const int gn = n0 + ni * 16;
#pragma unroll
            for (int r = 0; r < 4; ++r) {
                const int gm = m0 + mi * 16 + r;
                float v = acc[mi][ni][r];
                if constexpr (EPI == EPI_QKV) {
                    v += bias[gn];
                    ((u16*)Cv)[(long long)gm * ldc + gn] = f2bf(v);
                } else if constexpr (EPI == EPI_LOGITS) {
                    v = v * scale + (gm > gn ? NEG_INF_F : 0.0f);  // m=key, n=query
                    ((float*)Cv)[(long long)bz * cBatch + (long long)gm * ldc + gn] = v;
                } else if constexpr (EPI == EPI_CTX) {
                    ((u16*)Cv)[(long long)bz * cBatch + (long long)gm * ldc + gn] = f2bf(v);
                } else if constexpr (EPI == EPI_MLP) {
                    const long long idx = (long long)gm * ldc + gn;
                    v += bias[gn];
                    v = fmaxf(v, 0.0f);
                    float xv = bf2f(xb[idx]) + bf2f(ctxb[idx]) + v;
                    xb[idx] = f2bf(xv);
                } else {  // EPI_OUT
                    v += bias[gn];
                    ((float*)Cv)[(long long)gm * ldc + gn] = v;
                }
            }
        }
    }
}

// ---------------------------------------------------------------------------
// gemm3p: 3-buffer pipelined BT GEMM with the verified 8-phase-style skeleton
//   (T3 barrier-pair phases + T4 counted vmcnt + T5 setprio).
//   BM=256, BN=128, BK=64, 512 threads = 8 waves (4m x 2n, 64x64 C/wave).
//   LDS 144 KB: 3 x (A 32KB + B 16KB) rotating. Compute tile t from buf t%3
//   while staging tile t+2 into buf (t+2)%3 (write-after-read safe: that buf
//   was last read in tile t-1, all waves past it at tile-(t-1)'s final
//   barrier). Per K-tile: TWO phases, each
//     { ds_reads (C-level); 3x global_load_lds; s_barrier; lgkmcnt(0);
//       setprio(1); 16 MFMA; setprio(0); s_barrier }
//   with a single s_waitcnt vmcnt(6) at the tail of phase 2 (before the
//   tile-final barrier): forces tile t+1 landed for the next iteration's
//   reads while tile t+2's 6 loads stay in flight (never drains).
//   The s_barrier pairs pin the {read || stage || MFMA} interleave at the
//   HW level (the barrier-free variant was rescheduled by LLVM and lost 40%).
// ---------------------------------------------------------------------------
template <int EPI>
__global__ __launch_bounds__(512, 2) void gemm3p(
    const u16* __restrict__ A, int lda,
    const u16* __restrict__ Bw, int ldb,
    void* __restrict__ Cv, int ldc,
    int K, const float* __restrict__ bias,
    const u16* __restrict__ ctxb, u16* __restrict__ xb)
{
    __shared__ __align__(16) u16 sA[3][256 * 64];   // 3 x 32 KB
    __shared__ __align__(16) u16 sB[3][128 * 64];   // 3 x 16 KB

    const int tid  = threadIdx.x;
    const int wave = tid >> 6;
    const int lane = tid & 63;
    const int wm   = wave >> 1, wn = wave & 1;      // 4 x 2 wave grid
    const int quad = lane >> 4;
    const int rx7  = lane & 7;

    const int k8 = blockIdx.x & 7;
    const int r  = blockIdx.x >> 3;
    const int bxE = r >> 2;                         // n-tile (128 wide)
    const int byE = k8 * 4 + (r & 3);               // m-tile (256 tall)

    const u16* Ab = A  + (long long)(byE * 256) * lda;
    const u16* Bb = Bw + (long long)(bxE * 128) * ldb;

    // staging: call c covers rows c*64 + (tid>>3); 16B-group XOR swizzle.
    const int srow = tid >> 3;                      // 0..63
    const int gf   = (tid & 7) ^ ((tid >> 3) & 7);
    const long long aSrc = (long long)srow * lda + gf * 8;
    const long long bSrc = (long long)srow * ldb + gf * 8;
    const int dst = (wave << 9) + lane * 8;

#define STA(nb, c, k0) async_cp16(Ab + (long long)((c) * 64) * lda + (k0) + aSrc, \
                                  &sA[nb][(c) * 4096 + dst])
#define STB(nb, c, k0) async_cp16(Bb + (long long)((c) * 64) * ldb + (k0) + bSrc, \
                                  &sB[nb][(c) * 4096 + dst])

    const int ra = wm * 64 + (lane & 15);
    const int rb = wn * 64 + (lane & 15);

    floatx4 zero = {0.f, 0.f, 0.f, 0.f};
    floatx4 acc[4][4];
#pragma unroll
    for (int i = 0; i < 4; ++i)
#pragma unroll
        for (int j = 0; j < 4; ++j) acc[i][j] = zero;

    const int NT = K >> 6;                          // 16 for K=1024

    // prologue: tiles 0 (buf0) and 1 (buf1); rendezvous on tile 0 landed.
    STA(0, 0, 0);  STA(0, 1, 0);  STA(0, 2, 0);  STA(0, 3, 0);
    STB(0, 0, 0);  STB(0, 1, 0);
    STA(1, 0, 64); STA(1, 1, 64); STA(1, 2, 64); STA(1, 3, 64);
    STB(1, 0, 64); STB(1, 1, 64);
    asm volatile("s_waitcnt vmcnt(6)" ::: "memory");
    __builtin_amdgcn_s_barrier();

    int cb = 0;
    for (int t = 0; t < NT; ++t) {
        const int  nb = (cb == 0) ? 2 : cb - 1;     // (t+2) % 3
        const int  kn = (t + 2) << 6;
        const bool st = (t + 2) < NT;

        bf16x8 aF[2][4], bF[2][2];

        // ---- phase 1: n-frags 0,1 over full K=64 ----
#pragma unroll
        for (int h = 0; h < 2; ++h) {
            const int g = (((h << 2) + quad) ^ rx7) << 3;
#pragma unroll
            for (int mi = 0; mi < 4; ++mi)
                aF[h][mi] = *(const bf16x8*)&sA[cb][(ra + 16 * mi) * 64 + g];
#pragma unroll
            for (int ni = 0; ni < 2; ++ni)
                bF[h][ni] = *(const bf16x8*)&sB[cb][(rb + 16 * ni) * 64 + g];
        }
        if (st) { STA(nb, 0, kn); STA(nb, 1, kn); STA(nb, 2, kn); }
        __builtin_amdgcn_s_barrier();
        asm volatile("s_waitcnt lgkmcnt(0)" ::: "memory");
        __builtin_amdgcn_s_setprio(1);
#pragma unroll
        for (int h = 0; h < 2; ++h)
#pragma unroll
            for (int mi = 0; mi < 4; ++mi)
#pragma unroll
                for (int ni = 0; ni < 2; ++ni)
                    acc[mi][ni] = MFMA16(aF[h][mi], bF[h][ni], acc[mi][ni], 0, 0, 0);
        __builtin_amdgcn_s_setprio(0);
        __builtin_amdgcn_s_barrier();

        // ---- phase 2: n-frags 2,3 over full K=64 ----
        bf16x8 bG[2][2];
#pragma unroll
        for (int h = 0; h < 2; ++h) {
            const int g = (((h << 2) + quad) ^ rx7) << 3;
#pragma unroll
            for (int ni = 0; ni < 2; ++ni)
                bG[h][ni] = *(const bf16x8*)&sB[cb][(rb + 32 + 16 * ni) * 64 + g];
        }
        if (st) { STA(nb, 3, kn); STB(nb, 0, kn); STB(nb, 1, kn); }
        __builtin_amdgcn_s_barrier();
        asm volatile("s_waitcnt lgkmcnt(0)" ::: "memory");
        __builtin_amdgcn_s_setprio(1);
#pragma unroll
        for (int h = 0; h < 2; ++h)
#pragma unroll
            for (int mi = 0; mi < 4; ++mi)
#pragma unroll
                for (int ni = 0; ni < 2; ++ni)
                    acc[mi][2 + ni] = MFMA16(aF[h][mi], bG[h][ni], acc[mi][2 + ni], 0, 0, 0);
        __builtin_amdgcn_s_setprio(0);
        // force tile t+1 landed for next iteration's reads; tile t+2's 6
        // loads remain in flight across the barrier (never drain).
        asm volatile("s_waitcnt vmcnt(6)" ::: "memory");
        __builtin_amdgcn_s_barrier();

        cb = (cb == 2) ? 0 : cb + 1;
    }
#undef STA
#undef STB

    // epilogue: C/D layout col = lane&15, row = (lane>>4)*4 + reg
    const int m0 = byE * 256 + wm * 64 + (quad << 2);
    const int n0 = bxE * 128 + wn * 64 + (lane & 15);
#pragma unroll
    for (int mi = 0; mi < 4; ++mi) {
#pragma unroll
        for (int ni = 0; ni < 4; ++ni) {
            const int gn = n0 + ni * 16;
            const float bb = bias[gn];
#pragma unroll
            for (int rr = 0; rr < 4; ++rr) {
                const int gm = m0 + mi * 16 + rr;
                float v = acc[mi][ni][rr] + bb;
                if constexpr (EPI == EPI_QKV) {
                    ((u16*)Cv)[(long long)gm * ldc + gn] = f2bf(v);
                } else {  // EPI_MLP
                    const long long idx = (long long)gm * ldc + gn;
                    v = fmaxf(v, 0.0f);
                    float xv = bf2f(xb[idx]) + bf2f(ctxb[idx]) + v;
                    xb[idx] = f2bf(xv);
                }
            }
        }
    }
}

// ---------------------------------------------------------------------------
// Setup mega-kernel: weight transposes (f32->bf16) + bias packing.
// ---------------------------------------------------------------------------
template <int L, int H, int V>
__global__ void setup_weights(const float* __restrict__ Wq, const float* __restrict__ Wk,
                              const float* __restrict__ Wv, const float* __restrict__ Wm,
                              const float* __restrict__ Wout,
                              const float* __restrict__ bq, const float* __restrict__ bk,
                              const float* __restrict__ bv,
                              u16* __restrict__ WqkvT, u16* __restrict__ WmT,
                              u16* __restrict__ WoutT, float* __restrict__ bqkv)
{
    const int z = blockIdx.z;
    if (z == 4 * L + 1) {
        int i = ((blockIdx.y * 16 + blockIdx.x) * 256) + threadIdx.y * 64 + threadIdx.x;
        if (i < L * 3 * H) {
            int l = i / (3 * H), j = i % (3 * H);
            float v = (j < H) ? bq[l * H + j]
                    : (j < 2 * H) ? bk[l * H + j - H]
                                  : bv[l * H + j - 2 * H];
            bqkv[i] = v;
        }
        return;
    }

    const float* in;
    u16* outp;
    int inStride, outStride;
    if (z == 4 * L) {
        if (blockIdx.x >= V / 64) return;
        in = Wout; inStride = V;
        outp = WoutT; outStride = H;
    } else {
        const int which = z / L, l = z % L;
        inStride = H; outStride = H;
        if (which == 3) { in = Wm + (long long)l * H * H; outp = WmT + (long long)l * H * H; }
        else {
            in   = (which == 0 ? Wq : which == 1 ? Wk : Wv) + (long long)l * H * H;
            outp = WqkvT + (long long)l * 3 * H * H + (long long)which * H * H;
        }
    }

    __shared__ float tile[64][65];
    const int r0 = blockIdx.y * 64, c0 = blockIdx.x * 64;
    const int x = threadIdx.x, y = threadIdx.y;
#pragma unroll
    for (int j = 0; j < 16; ++j) {
        int r = y + j * 4;
        tile[r][x] = in[(long long)(r0 + r) * inStride + c0 + x];
    }
    __syncthreads();
#pragma unroll
    for (int j = 0; j < 16; ++j) {
        int r = y + j * 4;
        outp[(long long)(c0 + r) * outStride + r0 + x] = f2bf(tile[x][r]);
    }
}

// ---------------------------------------------------------------------------
// Merged attention post-processing (softmax + attnT, V->Vt transpose).
// ---------------------------------------------------------------------------
__global__ __launch_bounds__(1024) void attn_post(
    float* __restrict__ attn, long long aStride,
    u16* __restrict__ attnT, long long tStride,
    const u16* __restrict__ qkv, u16* __restrict__ Vt)
{
    const int zone = blockIdx.y;
    if (zone < 8) {
        __shared__ float sm[64][16], sl[64][16], sm2[8][16], sl2[8][16];
        __shared__ float sM[16], sInv[16];

        float* base = attn + (long long)zone * aStride;
        const int x = threadIdx.x, ky = threadIdx.y;
        const int q = blockIdx.x * 16 + x;

        float v[16];
        float m = -3.4e38f, l = 0.f;
#pragma unroll
        for (int j = 0; j < 16; ++j) {
            const int k = ky * 16 + j;
            float vj = NEG_INF_F;
            if (k <= q) vj = base[(long long)k * 1024 + q];
            v[j] = vj;
            float mn = fmaxf(m, vj);
            l = l * __expf(m - mn) + __expf(vj - mn);
            m = mn;
        }
        sm[ky][x] = m;
        sl[ky][x] = l;
        __syncthreads();
        if (ky < 8) {
            float M = -3.4e38f, L = 0.f;
#pragma unroll
            for (int t = 0; t < 8; ++t) {
                float mm = sm[ky + 8 * t][x], ll = sl[ky + 8 * t][x];
                float mn = fmaxf(M, mm);
                L = L * __expf(M - mn) + ll * __expf(mm - mn);
                M = mn;
            }
            sm2[ky][x] = M;
            sl2[ky][x] = L;
        }
        __syncthreads();
        if (ky == 0) {
            float M = -3.4e38f, L = 0.f;
#pragma unroll
            for (int t = 0; t < 8; ++t) {
                float mm = sm2[t][x], ll = sl2[t][x];
                float mn = fmaxf(M, mm);
                L = L * __expf(M - mn) + ll * __expf(mm - mn);
                M = mn;
            }
            sM[x]   = M;
            sInv[x] = 1.0f / L;
        }
        __syncthreads();
        const float M = sM[x], inv = sInv[x];

        u16 pb[16];
#pragma unroll
        for (int j = 0; j < 16; ++j) {
            float p = __expf(v[j] - M) * inv;
            base[(long long)(ky * 16 + j) * 1024 + q] = p;
            pb[j] = f2bf(p);
        }
        u16* trow = attnT + (long long)zone * tStride + (long long)q * 1024 + ky * 16;
        ((uint4*)trow)[0] = *(const uint4*)&pb[0];
        ((uint4*)trow)[1] = *(const uint4*)&pb[8];
    } else {
        const int b = zone - 8;
        const u16* Vb = qkv + 2 * 1024 + (long long)b * (1024LL * 3072);
        u16* Ob       = Vt + (long long)b * (1024LL * 1024);
        __shared__ float tile[64][65];
        const int tid = threadIdx.y * 16 + threadIdx.x;
        const int tx = tid & 63, ty = tid >> 6;
#pragma unroll
        for (int rep = 0; rep < 4; ++rep) {
            const int T = blockIdx.x + rep * 64;
            const int s0 = (T >> 4) * 64, h0 = (T & 15) * 64;
            __syncthreads();
#pragma unroll
            for (int j = 0; j < 4; ++j) {
                const int s = j * 16 + ty;
                tile[s][tx] = bf2f(Vb[(long long)(s0 + s) * 3072 + h0 + tx]);
            }
            __syncthreads();
#pragma unroll
            for (int j = 0; j < 4; ++j) {
                const int h = j * 16 + ty;
                Ob[(long long)(h0 + h) * 1024 + s0 + tx] = f2bf(tile[tx][h]);
            }
        }
    }
}

// ---------------------------------------------------------------------------
__global__ void embed_kernel(const int* __restrict__ tok, const float* __restrict__ emb,
                             u16* __restrict__ xb)
{
    const int row = blockIdx.x;
    const int t   = tok[row];
    float4 v = ((const float4*)(emb + (long long)t * 1024))[threadIdx.x];
    uint2 p;
    p.x = (u32)f2bf(v.x) | ((u32)f2bf(v.y) << 16);
    p.y = (u32)f2bf(v.z) | ((u32)f2bf(v.w) << 16);
    ((uint2*)(xb + (long long)row * 1024))[threadIdx.x] = p;
}

// ---------------------------------------------------------------------------
extern "C" void kernel_launch(void* const* d_in, const int* in_sizes, int n_in,
                              void* d_out, int out_size, void* d_ws, size_t ws_size,
                              hipStream_t stream)
{
    const int*   tok  = (const int*)d_in[0];
    const float* emb  = (const float*)d_in[1];
    const float* Wq   = (const float*)d_in[2];
    const float* bq   = (const float*)d_in[3];
    const float* Wk   = (const float*)d_in[4];
    const float* bk   = (const float*)d_in[5];
    const float* Wv   = (const float*)d_in[6];
    const float* bv   = (const float*)d_in[7];
    const float* Wm   = (const float*)d_in[8];
    const float* bm   = (const float*)d_in[9];
    const float* Wout = (const float*)d_in[10];
    const float* bout = (const float*)d_in[11];
    float* out = (float*)d_out;

    constexpr int B = 8, S = 1024, H = 1024, V = 512, L = 6;
    constexpr long long M = (long long)B * S;  // 8192

    char* ws = (char*)d_ws;
    u16*   WqkvT = (u16*)ws;   ws += (long long)L * 3 * H * H * 2;
    u16*   WmT   = (u16*)ws;   ws += (long long)L * H * H * 2;
    u16*   WoutT = (u16*)ws;   ws += (long long)V * H * 2;
    float* bqkv  = (float*)ws; ws += (long long)L * 3 * H * 4;
    u16*   xb    = (u16*)ws;   ws += M * H * 2;
    u16*   QKV   = (u16*)ws;   ws += M * 3 * H * 2;
    u16*   attnT = (u16*)ws;   ws += (long long)B * S * S * 2;
    u16*   Vt    = (u16*)ws;   ws += (long long)B * S * S * 2;
    u16*   ctxb  = (u16*)ws;   ws += M * H * 2;

    float* attnOut = out + (long long)B * S * V;

    setup_weights<L, H, V><<<dim3(16, 16, 4 * L + 2), dim3(64, 4), 0, stream>>>(
        Wq, Wk, Wv, Wm, Wout, bq, bk, bv, WqkvT, WmT, WoutT, bqkv);
    embed_kernel<<<M, 256, 0, stream>>>(tok, emb, xb);

    for (int l = 0; l < L; ++l) {
        // QKV = xb @ [Wq|Wk|Wv] + bias -> bf16 [M][3H]  (barrier-pair pipeline)
        gemm3p<EPI_QKV><<<768, 512, 0, stream>>>(
            xb, H, WqkvT + (long long)l * 3 * H * H, H,
            QKV, 3 * H, H, bqkv + l * 3 * H, nullptr, nullptr);

        // logits[k,q] = K . Q * scale + mask  (lower-triangle tiles, batch/XCD)
        float* attnL = attnOut + (long long)l * B * S * S;
        gemm_bt<EPI_LOGITS><<<288, 256, 0, stream>>>(
            QKV + H, 3 * H, (long long)S * 3 * H,
            QKV, 3 * H, (long long)S * 3 * H,
            attnL, S, (long long)S * S, H,
            nullptr, nullptr, nullptr, 0.03125f, 0, 0);

        // softmax+attnT emission (zones 0-7) and V->Vt transpose (zones 8-15)
        attn_post<<<dim3(64, 16), dim3(16, 64), 0, stream>>>(
            attnL, (long long)S * S, attnT, (long long)S * S, QKV, Vt);

        // ctx[q,h] = sum_{k<=q} attnT[q,k] * Vt[h,k]  -> bf16 (batch/XCD)
        gemm_bt<EPI_CTX><<<512, 256, 0, stream>>>(
            attnT, S, (long long)S * S, Vt, S, (long long)S * S,
            ctxb, H, (long long)S * H, S,
            nullptr, nullptr, nullptr, 0.f, 0, 0);

        // xb = bf16( xb + ctx + relu(ctx @ Wm + bm) )  (reverted to gemm_bt)
        gemm_bt<EPI_MLP><<<512, 256, 0, stream>>>(
            ctxb, H, 0, WmT + (long long)l * H * H, H, 0,
            nullptr, H, 0, H, bm + l * H, ctxb, xb, 0.f, 8, 64);
    }

    // out = xb @ Wout + bout -> f32
    gemm_bt<EPI_OUT><<<256, 256, 0, stream>>>(
        xb, H, 0, WoutT, H, 0, out, V, 0, H,
        bout, nullptr, nullptr, 0.f, 4, 64);
}